// Round 12
// baseline (888.674 us; speedup 1.0000x reference)
//
#include <hip/hip_runtime.h>
#include <cstdint>

// B=16, C=64, H=W=256. 3x3 convs via bf16 MFMA implicit GEMM.
// Round 12: A-frags (weights) in REGISTERS (18 global dwordx4/chunk from
// L2-hot packed buffer, issued before next-chunk staging so compiler's
// auto-vmcnt waits never drain the stage pipeline). LDS = pixel double-buffer
// only (52KB) -> 3 blocks/CU (12 waves/CU, was 8). Blocks: 256 thr / 4 waves
// / 1 output row. Convs separate; k_fin does the dynamic depthwise.
using short8  = __attribute__((ext_vector_type(8))) short;
using short4v = __attribute__((ext_vector_type(4))) short;
using f32x16  = __attribute__((ext_vector_type(16))) float;
using float4v = __attribute__((ext_vector_type(4))) float;
typedef unsigned short ushort_t;

#define CHUNK_ROW 520     // 65 macro-groups x 8 slots (16 ci per pixel)
#define CHUNK_SLOTS 1560  // 3 rows
#define BUF_SLOTS 1632    // padded (stage stripes overrun to 1617)
#define BUF_SHORTS (BUF_SLOTS * 8)

__device__ __forceinline__ float lrelu(float x) { return x > 0.f ? x : 0.1f * x; }

__device__ __forceinline__ ushort_t f2bf(float f) {
    union { float f; unsigned u; } v; v.f = f;
    unsigned r = (v.u + 0x7FFFu + ((v.u >> 16) & 1u)) >> 16;
    return (ushort_t)r;
}
__device__ __forceinline__ float bf2f(ushort_t b) {
    union { unsigned u; float f; } v; v.u = ((unsigned)b) << 16; return v.f;
}

// async 16B global -> LDS (dest = wave-uniform base; HW adds lane*16)
__device__ __forceinline__ void gload_lds16(const ushort_t* g, ushort_t* l) {
    __builtin_amdgcn_global_load_lds(
        (const __attribute__((address_space(1))) void*)g,
        (__attribute__((address_space(3))) void*)l, 16, 0, 0);
}

#define VMCNT(n) asm volatile("s_waitcnt vmcnt(" #n ")" ::: "memory")
#define RBAR() __builtin_amdgcn_s_barrier()
#define SCHED0() __builtin_amdgcn_sched_barrier(0)
#define PIN() asm volatile("" ::: "memory")

// ---------------------------------------------------------------------------
// Tiny branch: ktr[b][tap][c] = leaky(kern) * sigmoid-gate (mv folded in).
// ---------------------------------------------------------------------------
__global__ void k_tiny(const float* __restrict__ t, const float* __restrict__ tW1,
                       const float* __restrict__ tW2, const float* __restrict__ kW1,
                       const float* __restrict__ kW2, float* __restrict__ ktr) {
    int b = blockIdx.x;
    int c = threadIdx.x;  // 64
    __shared__ float h1[64], g1[64];
    float ts = t[b];
    h1[c] = lrelu(ts * tW1[c]);
    g1[c] = lrelu(ts * kW1[c]);
    __syncthreads();
    float s = 0.f;
    for (int j = 0; j < 64; ++j) s = fmaf(tW2[c * 64 + j], h1[j], s);
    float mvv = 1.f / (1.f + expf(-s));
    for (int q = 0; q < 9; ++q) {
        float s2 = 0.f;
        for (int j = 0; j < 64; ++j) s2 = fmaf(kW2[(c * 9 + q) * 64 + j], g1[j], s2);
        ktr[b * 576 + q * 64 + c] = lrelu(s2) * mvv;
    }
}

// ---------------------------------------------------------------------------
// Zero row buffer (edge-redirect source for staging).
// ---------------------------------------------------------------------------
__global__ void k_zrow(ushort_t* __restrict__ z) {
    int i = blockIdx.x * 256 + threadIdx.x;  // 2048 threads, 16384 shorts
    *(short8*)(z + (size_t)i * 8) = (short8)0;
}

// ---------------------------------------------------------------------------
// Pack three 64x64x3x3 weight tensors into MFMA A-fragment order (bf16).
// flat = ((t*4 + chunk)*2 + ct)*512 + lane*8 + j
//   = W[co = ct*32 + (lane&31)][ci = chunk*16 + (lane>>5)*8 + j], tap t
// ---------------------------------------------------------------------------
__global__ void k_pack(const float* __restrict__ w1, const float* __restrict__ w2,
                       const float* __restrict__ w3, ushort_t* __restrict__ wp) {
    int idx = blockIdx.x * 256 + threadIdx.x;
    if (idx >= 3 * 36864) return;
    int conv = idx / 36864, r = idx % 36864;
    const float* W = conv == 0 ? w1 : (conv == 1 ? w2 : w3);
    int j = r & 7, lane = (r >> 3) & 63, ct = (r >> 9) & 1, chunk = (r >> 10) & 3,
        t = r >> 12;
    int co = ct * 32 + (lane & 31);
    int ci = chunk * 16 + (lane >> 5) * 8 + j;
    wp[idx] = f2bf(W[(co * 64 + ci) * 9 + t]);
}

// ---------------------------------------------------------------------------
// Transpose x: fp32 NCHW -> bf16 NHWC (width-256 rows). Block = (b,h).
// ---------------------------------------------------------------------------
__global__ __launch_bounds__(256) void k_tr(const float* __restrict__ x,
                                            ushort_t* __restrict__ xbf) {
    int bid = blockIdx.x;
    int h = bid & 255, b = bid >> 8;
    int t = threadIdx.x;
    for (int it = 0; it < 8; ++it) {
        int idx = t + it * 256;  // (w, g)
        int g = idx & 7, w = idx >> 3;
        const float* src = x + (((size_t)(b * 64 + g * 8) * 256 + h) * 256 + w);
        short8 v;
#pragma unroll
        for (int j = 0; j < 8; ++j) v[j] = (short)f2bf(src[(size_t)j * 65536]);
        *(short8*)(xbf + (((size_t)(b * 256 + h) * 256 + w) * 64 + g * 8)) = v;
    }
}

// ---------------------------------------------------------------------------
// Stage one 16-ci chunk: 3 rows x 258 pix, 7 x gload_lds16 per wave (4 waves,
// stripes of 390 slots). Inverse swizzle baked into per-lane source address.
// ---------------------------------------------------------------------------
#define STAGE_CHUNK(chunk, bufbase)                                              \
    {                                                                            \
        _Pragma("unroll")                                                        \
        for (int i_ = 0; i_ < 7; ++i_) {                                         \
            int base_ = wv * 390 + i_ * 64;                                      \
            int S_ = base_ + lane;                                               \
            S_ = S_ < CHUNK_SLOTS ? S_ : CHUNK_SLOTS - 1;                        \
            int row_ = (S_ >= 2 * CHUNK_ROW) ? 2 : (S_ >= CHUNK_ROW ? 1 : 0);    \
            int rem_ = S_ - row_ * CHUNK_ROW;                                    \
            int mg_ = rem_ >> 3, sl_ = rem_ & 7;                                 \
            int sp_ = sl_ ^ (mg_ & 7);                                           \
            int p_ = mg_ * 4 + (sp_ >> 1), g_ = sp_ & 1;                         \
            int wsx_ = p_ - 1;                                                   \
            bool edge_ = (unsigned)wsx_ >= 256u;                                 \
            const ushort_t* rp_ = (row_ == 0) ? rb0 : (row_ == 1 ? rb1 : rb2);   \
            const ushort_t* src_ =                                               \
                edge_ ? zv : (rp_ + wsx_ * 64 + (chunk)*16 + g_ * 8);            \
            gload_lds16(src_, xs + (bufbase) + (size_t)base_ * 8);               \
        }                                                                        \
    }

// Load all 18 A-fragments (9 taps x 2 c_out tiles) of one chunk into regs.
#define LOADA(chunk)                                                             \
    {                                                                            \
        _Pragma("unroll")                                                        \
        for (int t_ = 0; t_ < 9; ++t_) {                                         \
            const ushort_t* wf_ =                                                \
                wp + ((size_t)(t_ * 4 + (chunk)) * 2) * 512 + lane * 8;          \
            aw[t_][0] = *(const short8*)(wf_);                                   \
            aw[t_][1] = *(const short8*)(wf_ + 512);                             \
        }                                                                        \
    }

// Compute one chunk: B from LDS (2 ds_read_b128/tap), A from registers.
#define COMPUTE(xbase)                                                           \
    {                                                                            \
        __builtin_amdgcn_s_setprio(1);                                           \
        _Pragma("unroll")                                                        \
        for (int t_ = 0; t_ < 9; ++t_) {                                         \
            const int dwx_ = t_ % 3, rr_ = t_ / 3;                               \
            _Pragma("unroll")                                                    \
            for (int pt_ = 0; pt_ < 2; ++pt_) {                                  \
                int p_ = pw0 + pt_ * 32 + l31 + dwx_;                            \
                int mg_ = p_ >> 2;                                               \
                int sl_ = ((p_ & 3) * 2 + lhi) ^ (mg_ & 7);                      \
                short8 bf = *(const short8*)(                                    \
                    xs + (xbase) + (size_t)(rr_ * CHUNK_ROW + mg_ * 8 + sl_) * 8);\
                acc[0][pt_] = __builtin_amdgcn_mfma_f32_32x32x16_bf16(           \
                    aw[t_][0], bf, acc[0][pt_], 0, 0, 0);                        \
                acc[1][pt_] = __builtin_amdgcn_mfma_f32_32x32x16_bf16(           \
                    aw[t_][1], bf, acc[1][pt_], 0, 0, 0);                        \
            }                                                                    \
        }                                                                        \
        __builtin_amdgcn_s_setprio(0);                                           \
    }

// ---------------------------------------------------------------------------
// 3x3 conv 64->64. Block = (b,h) XCD-swizzled, 4 waves, each 64co x 64pix.
// OMODE: 0 = bf16 NHWC + leaky; 1 = bf16 NCHW + leaky; 2 = fp32 NCHW + bias.
// ---------------------------------------------------------------------------
template <int OMODE>
__global__ __launch_bounds__(256, 3) void k_conv(
    const ushort_t* __restrict__ in, const ushort_t* __restrict__ zv,
    const ushort_t* __restrict__ wp, const float* __restrict__ bias,
    void* __restrict__ outp) {
    __shared__ __align__(16) ushort_t xs[2 * BUF_SHORTS];  // 52224 B
    const int tid = threadIdx.x;
    const int lane = tid & 63;
    const int wv = tid >> 6;  // 0..3
    const unsigned bid = blockIdx.x;
    const unsigned L = (bid & 7u) * 512u + (bid >> 3);  // 4096 = 8*512 bijective
    const int h = L & 255, b = L >> 8;
    const int l31 = lane & 31, lhi = lane >> 5;
    const int pw0 = wv * 64;

    const ushort_t* rb0 = (h > 0)   ? in + ((size_t)(b * 256 + h - 1)) * 16384 : zv;
    const ushort_t* rb1 =             in + ((size_t)(b * 256 + h)) * 16384;
    const ushort_t* rb2 = (h < 255) ? in + ((size_t)(b * 256 + h + 1)) * 16384 : zv;

    f32x16 acc[2][2];
#pragma unroll
    for (int a = 0; a < 2; ++a)
#pragma unroll
        for (int c = 0; c < 2; ++c) acc[a][c] = (f32x16)0.0f;

    short8 aw[9][2];

    // ---- phase 0 ----
    LOADA(0);
    PIN();                 // A(0) stays older than all staging
    STAGE_CHUNK(0, 0);
    STAGE_CHUNK(1, BUF_SHORTS);
    VMCNT(7);              // retire A(0)+S(0); S(1) stays in flight
    RBAR(); SCHED0();
    COMPUTE(0);
    // ---- phase 1 ----
    LOADA(1);
    PIN();
    VMCNT(18);             // retire S(1); A(1) 18 stay in flight
    RBAR(); SCHED0();
    STAGE_CHUNK(2, 0);
    COMPUTE(BUF_SHORTS);
    // ---- phase 2 ----
    LOADA(2);
    PIN();
    VMCNT(18);             // retire S(2); A(2) in flight
    RBAR(); SCHED0();
    STAGE_CHUNK(3, BUF_SHORTS);
    COMPUTE(0);
    // ---- phase 3 ----
    LOADA(3);
    PIN();
    VMCNT(18);             // retire S(3); A(3) in flight
    RBAR(); SCHED0();
    COMPUTE(BUF_SHORTS);

    // Epilogue. D layout: col(pix)=lane&31, row(co)=(reg&3)+8*(reg>>2)+4*(lane>>5)
    const int co_b = 4 * lhi;
    if (OMODE == 0) {
        ushort_t* outb = (ushort_t*)outp + ((size_t)(b * 256 + h)) * 16384;
#pragma unroll
        for (int ct = 0; ct < 2; ++ct)
#pragma unroll
            for (int pt = 0; pt < 2; ++pt) {
                int pix = pw0 + pt * 32 + l31;
                ushort_t* po = outb + (size_t)pix * 64 + ct * 32 + co_b;
#pragma unroll
                for (int q = 0; q < 4; ++q) {
                    float4v bv = *(const float4v*)(bias + ct * 32 + co_b + 8 * q);
                    short4v sv;
#pragma unroll
                    for (int m = 0; m < 4; ++m) {
                        float v = lrelu(acc[ct][pt][q * 4 + m] + bv[m]);
                        sv[m] = (short)f2bf(v);
                    }
                    *(short4v*)(po + 8 * q) = sv;
                }
            }
    } else if (OMODE == 1) {
        ushort_t* pb = (ushort_t*)outp + (((size_t)b * 64) << 16) + h * 256;
#pragma unroll
        for (int ct = 0; ct < 2; ++ct)
#pragma unroll
            for (int pt = 0; pt < 2; ++pt) {
                int pix = pw0 + pt * 32 + l31;
#pragma unroll
                for (int q = 0; q < 4; ++q) {
                    float4v bv = *(const float4v*)(bias + ct * 32 + co_b + 8 * q);
#pragma unroll
                    for (int m = 0; m < 4; ++m) {
                        int c = ct * 32 + co_b + 8 * q + m;
                        float v = lrelu(acc[ct][pt][q * 4 + m] + bv[m]);
                        pb[((size_t)c << 16) + pix] = f2bf(v);
                    }
                }
            }
    } else {
        float* pb = (float*)outp + (((size_t)b * 64) << 16) + h * 256;
#pragma unroll
        for (int ct = 0; ct < 2; ++ct)
#pragma unroll
            for (int pt = 0; pt < 2; ++pt) {
                int pix = pw0 + pt * 32 + l31;
#pragma unroll
                for (int q = 0; q < 4; ++q) {
                    float4v bv = *(const float4v*)(bias + ct * 32 + co_b + 8 * q);
#pragma unroll
                    for (int m = 0; m < 4; ++m) {
                        int c = ct * 32 + co_b + 8 * q + m;
                        pb[((size_t)c << 16) + pix] = acc[ct][pt][q * 4 + m] + bv[m];
                    }
                }
            }
    }
}

// ---------------------------------------------------------------------------
// Final depthwise: out[b][c][h][w] += sum_tap ktr[b][tap][c] * f2[b][c][h'][w']
// Block = (b, c, 8-row band); f2 is bf16 NCHW. High occupancy.
// ---------------------------------------------------------------------------
__global__ __launch_bounds__(256) void k_fin(const ushort_t* __restrict__ f2,
                                             const float* __restrict__ ktr,
                                             float* __restrict__ out) {
    __shared__ __align__(16) ushort_t s[10 * 272];
    const unsigned bid = blockIdx.x;
    const unsigned L = (bid & 7u) * 4096u + (bid >> 3);  // bijective, 32768=8*4096
    const int hb = L & 31, c = (L >> 5) & 63, b = L >> 11;
    const int h0 = hb * 8;
    const int w = threadIdx.x;

    const ushort_t* f2c = f2 + (((size_t)(b * 64 + c)) << 16);
    for (int i = w; i < 320; i += 256) {
        int r = i >> 5, seg = i & 31;
        int hs = h0 - 1 + r;
        short8 v = (short8)0;
        if ((unsigned)hs < 256u) v = *(const short8*)(f2c + hs * 256 + seg * 8);
        *(short8*)(&s[r * 272 + 8 + seg * 8]) = v;
        if (seg == 0) s[r * 272 + 7] = 0;
        if (seg == 31) s[r * 272 + 264] = 0;
    }
    __syncthreads();

    float kv[9];
#pragma unroll
    for (int t9 = 0; t9 < 9; ++t9) kv[t9] = ktr[b * 576 + t9 * 64 + c];

    float lv[10], cv[10], rv[10];
#pragma unroll
    for (int r = 0; r < 10; ++r) {
        lv[r] = bf2f(s[r * 272 + 7 + w]);
        cv[r] = bf2f(s[r * 272 + 8 + w]);
        rv[r] = bf2f(s[r * 272 + 9 + w]);
    }

    float* ob = out + (((size_t)(b * 64 + c)) << 16) + h0 * 256 + w;
#pragma unroll
    for (int rr = 0; rr < 8; ++rr) {
        float dwv = 0.f;
#pragma unroll
        for (int r3 = 0; r3 < 3; ++r3) {
            dwv = fmaf(kv[r3 * 3 + 0], lv[rr + r3], dwv);
            dwv = fmaf(kv[r3 * 3 + 1], cv[rr + r3], dwv);
            dwv = fmaf(kv[r3 * 3 + 2], rv[rr + r3], dwv);
        }
        float* po = ob + rr * 256;
        *po = *po + dwv;
    }
}

// ---------------------------------------------------------------------------
extern "C" void kernel_launch(void* const* d_in, const int* in_sizes, int n_in,
                              void* d_out, int out_size, void* d_ws, size_t ws_size,
                              hipStream_t stream) {
    const float* x   = (const float*)d_in[0];
    const float* t   = (const float*)d_in[1];
    const float* tW1 = (const float*)d_in[2];
    const float* tW2 = (const float*)d_in[3];
    const float* fW1 = (const float*)d_in[4];
    const float* fb1 = (const float*)d_in[5];
    const float* fW2 = (const float*)d_in[6];
    const float* fb2 = (const float*)d_in[7];
    const float* kW1 = (const float*)d_in[8];
    const float* kW2 = (const float*)d_in[9];
    const float* cW  = (const float*)d_in[10];
    const float* cb  = (const float*)d_in[11];

    // ws: [ktr 36K @0][wp 216K @65536][zv 32K @294912]
    //     [R1 128MB @512K]: xbf (until conv3 done), then f2
    //     [R2 128MB @512K+128MB]: f1
    char* ws = (char*)d_ws;
    float*    ktr  = (float*)ws;
    ushort_t* wp   = (ushort_t*)(ws + 65536);
    ushort_t* zv   = (ushort_t*)(ws + 294912);
    ushort_t* xbf  = (ushort_t*)(ws + (512u << 10));                       // R1
    ushort_t* f1bf = (ushort_t*)(ws + (512u << 10) + ((size_t)128 << 20)); // R2
    ushort_t* f2n  = xbf;  // R1 reused after conv3 (last xbf reader) finishes
    float*    out  = (float*)d_out;

    k_tiny<<<dim3(16), dim3(64), 0, stream>>>(t, tW1, tW2, kW1, kW2, ktr);
    k_zrow<<<dim3(8), dim3(256), 0, stream>>>(zv);
    k_pack<<<dim3((3 * 36864 + 255) / 256), dim3(256), 0, stream>>>(fW1, fW2, cW, wp);
    k_tr<<<dim3(4096), dim3(256), 0, stream>>>(x, xbf);

    // conv1: x -> f1 (bf16 NHWC); conv3: x -> d_out (fp32 NCHW, +cb);
    // conv2: f1 -> f2 (bf16 NCHW); k_fin: out += dw(f2)*gate.
    k_conv<0><<<dim3(4096), dim3(256), 0, stream>>>(xbf, zv, wp, fb1, (void*)f1bf);
    k_conv<2><<<dim3(4096), dim3(256), 0, stream>>>(xbf, zv, wp + 2 * 36864, cb, (void*)out);
    k_conv<1><<<dim3(4096), dim3(256), 0, stream>>>(f1bf, zv, wp + 36864, fb2, (void*)f2n);
    k_fin<<<dim3(32768), dim3(256), 0, stream>>>(f2n, ktr, out);
}